// Round 2
// baseline (299.255 us; speedup 1.0000x reference)
//
#include <hip/hip_runtime.h>
#include <hip/hip_cooperative_groups.h>

namespace cg = cooperative_groups;

// GuidedMoEBasic: B=16, D=64, H=768, NE=7, FEAT=776, 2*FEAT=1552
// P = D*(D+1)/2 = 2080 pairs/batch, N = 16*2080 = 33280.
//
// Algebraic collapse: expert MLP is affine end-to-end, so
//   o[e,n,:] = flat[n] @ (W1[e]@W2[e]) + (b1[e]@W2[e] + b2[e])
// and flat[n] = [conc[b,t], conc[b,end]] reduces everything to
// per-utterance 12-float precomputed vectors (pc). Single cooperative
// kernel: phaseA builds M=W1@W2, phaseB builds pc per row, phaseC does
// O(1) work per pair. Two grid.sync()s replace two kernel launches.

#define H_     768
#define NE_    7
#define FEAT_  776
#define TWOF   1552
#define NROW   1024
#define PAIRS  2080
#define NPAIR  33280
#define EXH    256

// workspace float layout
#define M_OFF  0        // 2*1552*2 = 6208 floats  (M[e][r][c])
#define BC_OFF 6208     // 4 floats                 (bconst[e][c])
#define PC_OFF 6212     // 1024*12 floats           (pc[row][j])

__global__ __launch_bounds__(256, 4) void kAll(
        const float* __restrict__ pooled,
        const int*   __restrict__ spk,
        const float* __restrict__ emo_w,
        const float* __restrict__ emo_b,
        const float* __restrict__ gate_w,
        const float* __restrict__ gate_b,
        const float* __restrict__ w1,
        const float* __restrict__ b1,
        const float* __restrict__ w2,
        const float* __restrict__ b2,
        float* __restrict__ out,      // [1024*7] emotion | [33280*2] cause
        float* __restrict__ ws) {
    cg::grid_group grid = cg::this_grid();

    float* M  = ws + M_OFF;
    float* bc = ws + BC_OFF;
    float* pc = ws + PC_OFF;

    const int t    = threadIdx.x;
    const int lane = t & 63;
    const int wave = t >> 6;

    // ---------------- Phase A: M[e][r][c] = sum_h W1[e][r][h]*W2[e][h][c]
    // one wave per row; rows 0..3103 = M, rows 3104/3105 = bias rows.
    {
        const int gw = blockIdx.x * 4 + wave;     // 0..4095
        if (gw < 3106) {
            int e, r = 0;
            float4 a;
            if (gw < 3104) {
                e = gw / TWOF;
                r = gw - e * TWOF;
                a = ((const float4*)(w1 + ((size_t)e * TWOF + r) * EXH))[lane];
            } else {
                e = gw - 3104;
                a = ((const float4*)(b1 + e * EXH))[lane];
            }
            const float4* wv = (const float4*)(w2 + (size_t)e * EXH * 2);
            const float4 q0 = wv[lane * 2];
            const float4 q1 = wv[lane * 2 + 1];
            float a0 = a.x * q0.x + a.y * q0.z + a.z * q1.x + a.w * q1.z;
            float a1 = a.x * q0.y + a.y * q0.w + a.z * q1.y + a.w * q1.w;
#pragma unroll
            for (int off = 32; off; off >>= 1) {
                a0 += __shfl_down(a0, off);
                a1 += __shfl_down(a1, off);
            }
            if (lane == 0) {
                if (gw < 3104) {
                    M[((size_t)e * TWOF + r) * 2 + 0] = a0;
                    M[((size_t)e * TWOF + r) * 2 + 1] = a1;
                } else {
                    bc[e * 2 + 0] = a0 + b2[e * 2 + 0];
                    bc[e * 2 + 1] = a1 + b2[e * 2 + 1];
                }
            }
        }
    }

    __threadfence();
    grid.sync();

    // ---------------- Phase B: one block per utterance row.
    {
        __shared__ float conc[FEAT_];
        __shared__ float redE[4][NE_];
        __shared__ float redP[4][12];

        const int row = blockIdx.x;               // grid is exactly NROW blocks
        const float* prow = pooled + (size_t)row * H_;

        float acc[NE_] = {0.f, 0.f, 0.f, 0.f, 0.f, 0.f, 0.f};
        for (int i = t; i < H_; i += 256) {
            const float p = prow[i];
            conc[i] = p;
#pragma unroll
            for (int k = 0; k < NE_; k++) acc[k] += p * emo_w[i * NE_ + k];
        }
#pragma unroll
        for (int off = 32; off; off >>= 1)
#pragma unroll
            for (int k = 0; k < NE_; k++) acc[k] += __shfl_down(acc[k], off);
        if (lane == 0)
#pragma unroll
            for (int k = 0; k < NE_; k++) redE[wave][k] = acc[k];
        __syncthreads();

        if (t < NE_) {
            const float v = emo_b[t] + redE[0][t] + redE[1][t] + redE[2][t] + redE[3][t];
            out[row * NE_ + t] = v;
            conc[H_ + t] = v;
        } else if (t == NE_) {
            conc[FEAT_ - 1] = (float)spk[row];
        }
        __syncthreads();

        float pa[12] = {0.f, 0.f, 0.f, 0.f, 0.f, 0.f, 0.f, 0.f, 0.f, 0.f, 0.f, 0.f};
        for (int f = t; f < FEAT_; f += 256) {
            const float c = conc[f];
            const float* a0 = M + f * 2;                     // e0, top half
            const float* a1 = M + (TWOF + f) * 2;            // e1, top half
            const float* b0 = M + (FEAT_ + f) * 2;           // e0, bottom half
            const float* b1r = M + (TWOF + FEAT_ + f) * 2;   // e1, bottom half
            pa[0]  += c * a0[0];  pa[1]  += c * a0[1];
            pa[2]  += c * a1[0];  pa[3]  += c * a1[1];
            pa[4]  += c * b0[0];  pa[5]  += c * b0[1];
            pa[6]  += c * b1r[0]; pa[7]  += c * b1r[1];
            pa[8]  += c * gate_w[f * 2];              pa[9]  += c * gate_w[f * 2 + 1];
            pa[10] += c * gate_w[(FEAT_ + f) * 2];    pa[11] += c * gate_w[(FEAT_ + f) * 2 + 1];
        }
#pragma unroll
        for (int off = 32; off; off >>= 1)
#pragma unroll
            for (int k = 0; k < 12; k++) pa[k] += __shfl_down(pa[k], off);
        if (lane == 0)
#pragma unroll
            for (int k = 0; k < 12; k++) redP[wave][k] = pa[k];
        __syncthreads();

        if (t < 12)
            pc[row * 12 + t] = redP[0][t] + redP[1][t] + redP[2][t] + redP[3][t];
    }

    __threadfence();
    grid.sync();

    // ---------------- Phase C: one thread per pair, O(1) combine.
    {
        const int n = blockIdx.x * 256 + t;
        if (n < NPAIR) {
            const int b = n / PAIRS;
            const int p = n - b * PAIRS;

            int end = (int)((sqrtf(8.0f * (float)p + 1.0f) - 1.0f) * 0.5f);
            while ((end + 1) * (end + 2) / 2 <= p) end++;
            while (end * (end + 1) / 2 > p) end--;
            const int tt = p - end * (end + 1) / 2;

            const float* pt = pc + ((size_t)b * 64 + tt) * 12;
            const float* pe = pc + ((size_t)b * 64 + end) * 12;

            const float g0 = pt[8] + pe[10] + gate_b[0];
            const float g1 = pt[9] + pe[11] + gate_b[1];

            const float o00 = pt[0] + pe[4] + bc[0];
            const float o01 = pt[1] + pe[5] + bc[1];
            const float o10 = pt[2] + pe[6] + bc[2];
            const float o11 = pt[3] + pe[7] + bc[3];

            float* oc = out + NROW * NE_;
            oc[(size_t)n * 2 + 0] = o00 * g0 + o10 * g1;
            oc[(size_t)n * 2 + 1] = o01 * g0 + o11 * g1;
        }
    }
}

// ---------------------------------------------------------------------------
extern "C" void kernel_launch(void* const* d_in, const int* in_sizes, int n_in,
                              void* d_out, int out_size, void* d_ws, size_t ws_size,
                              hipStream_t stream) {
    const float* pooled = (const float*)d_in[0];
    const int*   spk    = (const int*)d_in[1];
    const float* emo_w  = (const float*)d_in[2];
    const float* emo_b  = (const float*)d_in[3];
    const float* gate_w = (const float*)d_in[4];
    const float* gate_b = (const float*)d_in[5];
    const float* exp_w1 = (const float*)d_in[6];
    const float* exp_b1 = (const float*)d_in[7];
    const float* exp_w2 = (const float*)d_in[8];
    const float* exp_b2 = (const float*)d_in[9];

    float* out = (float*)d_out;
    float* ws  = (float*)d_ws;

    void* args[] = {
        (void*)&pooled, (void*)&spk, (void*)&emo_w, (void*)&emo_b,
        (void*)&gate_w, (void*)&gate_b, (void*)&exp_w1, (void*)&exp_b1,
        (void*)&exp_w2, (void*)&exp_b2, (void*)&out, (void*)&ws,
    };
    hipLaunchCooperativeKernel((void*)kAll, dim3(NROW), dim3(256), args, 0, stream);
}

// Round 3
// 36.090 us; speedup vs baseline: 8.2919x; 8.2919x over previous
//
#include <hip/hip_runtime.h>

// GuidedMoEBasic single-kernel: B=16, D=64, H=768, NE=7, FEAT=776.
// Expert MLP is affine end-to-end -> collapse to Bt[12][776] coefficient matrix
// (8 M-columns from W1@W2 + 4 gate columns), pc[row][12] = conc[row] @ Bt^T,
// cause per pair is O(1) from pc. One launch: 48 publisher blocks build Bt (bf16,
// chunked layout in ws), 16 batch blocks do emotion-MFMA + projection-MFMA + pairs,
// synchronized by a device-global arrive/depart counter (replay-safe, poison-safe).

#define NPUB   48
#define NBATCH 16
#define H_     768
#define NE_    7
#define FEAT_  776
#define NROW   1024
#define PAIRS  2080
#define EXH    256
#define CHW    256          // k-chunk width
#define CST    264          // chunk row stride in shorts (bank padding)
#define NJ     12

__device__ int g_arrive = 0;
__device__ int g_depart = 0;

typedef float f32x4 __attribute__((ext_vector_type(4)));
typedef short bf16x8 __attribute__((ext_vector_type(8)));

__device__ __forceinline__ unsigned short f2b(float x) {
    unsigned u = __float_as_uint(x);
    u += 0x7FFFu + ((u >> 16) & 1u);
    return (unsigned short)(u >> 16);
}

__global__ __launch_bounds__(256) void kFused(
        const float* __restrict__ pooled,
        const int*   __restrict__ spk,
        const float* __restrict__ emo_w,
        const float* __restrict__ emo_b,
        const float* __restrict__ gate_w,
        const float* __restrict__ gate_b,
        const float* __restrict__ w1,
        const float* __restrict__ b1,
        const float* __restrict__ w2,
        const float* __restrict__ b2,
        float* __restrict__ out,                 // [1024*7] emo | [33280*2] cause
        unsigned short* __restrict__ wsbt,       // [4][12][264] bf16
        float* __restrict__ wsbc) {              // [4] bias consts
    const int blk  = blockIdx.x;
    const int tid  = threadIdx.x;
    const int lane = tid & 63;
    const int wv   = tid >> 6;

    __shared__ short smem[24224];                 // 48,448 B

    if (blk < NPUB) {
        // ================= publisher =================
        // M rows: 3104 dot-pairs (e, rr): M[.]=W1[e][rr][:]·W2[e][:][c] -> Bt bf16
        const int rend = (blk * 65 + 65 < 3104) ? blk * 65 + 65 : 3104;
        for (int row = blk * 65 + wv; row < rend; row += 4) {
            const int e = row / 1552, rr = row - e * 1552;
            const float4 a = ((const float4*)(w1 + ((size_t)e * 1552 + rr) * EXH))[lane];
            const float4* wvp = (const float4*)(w2 + (size_t)e * EXH * 2);
            const float4 q0 = wvp[lane * 2], q1 = wvp[lane * 2 + 1];
            float a0 = a.x * q0.x + a.y * q0.z + a.z * q1.x + a.w * q1.z;
            float a1 = a.x * q0.y + a.y * q0.w + a.z * q1.y + a.w * q1.w;
#pragma unroll
            for (int off = 32; off; off >>= 1) {
                a0 += __shfl_down(a0, off);
                a1 += __shfl_down(a1, off);
            }
            if (lane == 0) {
                const int half = rr / FEAT_, f = rr - half * FEAT_;
                const int ch  = (f < 768) ? (f >> 8) : 3;
                const int rel = (f < 768) ? (f & 255) : (f - 768);
                const int j = half * 4 + e * 2;
                wsbt[(ch * NJ + j) * CST + rel]       = f2b(a0);
                wsbt[(ch * NJ + j + 1) * CST + rel]   = f2b(a1);
            }
        }
        // gate columns -> Bt rows 8..11
        for (int g = blk * 256 + tid; g < 3104; g += NPUB * 256) {
            const int half = g / 1552, r2 = g - half * 1552, f = r2 >> 1, c = r2 & 1;
            const int ch  = (f < 768) ? (f >> 8) : 3;
            const int rel = (f < 768) ? (f & 255) : (f - 768);
            wsbt[(ch * NJ + 8 + half * 2 + c) * CST + rel] = f2b(gate_w[(half * FEAT_ + f) * 2 + c]);
        }
        // zero pad cells (chunk3 rel 8..263 all j; chunks 0-2 rel 256..263 all j)
        for (int z = blk * 256 + tid; z < 3360; z += NPUB * 256) {
            int ch, j, rel;
            if (z < 3072) { ch = 3; j = z >> 8; rel = 8 + (z & 255); }
            else { const int z2 = z - 3072; ch = z2 / 96; j = (z2 % 96) >> 3; rel = 256 + (z2 & 7); }
            wsbt[(ch * NJ + j) * CST + rel] = 0;
        }
        // bias consts (block 0, waves 0/1): bc[e][c] = b1[e]·W2[e][:,c] + b2[e][c]
        if (blk == 0 && wv < 2) {
            const int e = wv;
            const float4 a = ((const float4*)(b1 + e * EXH))[lane];
            const float4* wvp = (const float4*)(w2 + (size_t)e * EXH * 2);
            const float4 q0 = wvp[lane * 2], q1 = wvp[lane * 2 + 1];
            float a0 = a.x * q0.x + a.y * q0.z + a.z * q1.x + a.w * q1.z;
            float a1 = a.x * q0.y + a.y * q0.w + a.z * q1.y + a.w * q1.w;
#pragma unroll
            for (int off = 32; off; off >>= 1) {
                a0 += __shfl_down(a0, off);
                a1 += __shfl_down(a1, off);
            }
            if (lane == 0) {
                wsbc[e * 2]     = a0 + b2[e * 2];
                wsbc[e * 2 + 1] = a1 + b2[e * 2 + 1];
            }
        }
        __syncthreads();
        __threadfence();
        if (tid == 0)
            __hip_atomic_fetch_add(&g_arrive, 1, __ATOMIC_RELEASE, __HIP_MEMORY_SCOPE_AGENT);
        return;
    }

    // ================= batch block =================
    const int b  = blk - NPUB;
    const int R0 = b * 64;
    short* concC = smem;                       // [64][264] bf16
    short* btE   = smem + 16896;               // [8][264]  bf16 (emo_w^T chunk)
    short* btM   = smem + 19008;               // [12][264] bf16 (Bt chunk)
    float* pcT   = (float*)(smem + 22176);     // [64][8]
    float* pcE   = pcT + 512;                  // [64][8]

    const int col = lane & 15, q = lane >> 4;
    f32x4 accE = {0.f, 0.f, 0.f, 0.f};
    f32x4 acc2 = {0.f, 0.f, 0.f, 0.f};
    bool synced = false;

    for (int ch = 0; ch < 4; ++ch) {
        if (ch < 3) {
            // stage pooled chunk -> concC bf16
            for (int i = 0; i < 16; ++i) {
                const int s = tid + i * 256;          // 0..4095
                const int row = s >> 6, c4 = s & 63;
                const float4 v = *(const float4*)(pooled + (size_t)(R0 + row) * H_ + ch * CHW + c4 * 4);
                short4 o;
                o.x = (short)f2b(v.x); o.y = (short)f2b(v.y);
                o.z = (short)f2b(v.z); o.w = (short)f2b(v.w);
                *(short4*)(concC + row * CST + c4 * 4) = o;
            }
            // stage emo_w^T chunk (rows 0..6 real; row 7+ garbage-unused)
            for (int i2 = tid; i2 < 7 * 256; i2 += 256) {
                const int c = i2 >> 8, rel = i2 & 255;
                btE[c * CST + rel] = (short)f2b(emo_w[(ch * CHW + rel) * NE_ + c]);
            }
        }
        if (!synced) {
            if (tid == 0) {
                while (__hip_atomic_load(&g_arrive, __ATOMIC_ACQUIRE, __HIP_MEMORY_SCOPE_AGENT) < NPUB)
                    __builtin_amdgcn_s_sleep(8);
            }
            __syncthreads();
            __threadfence();
            if (tid == 0) {
                const int d = __hip_atomic_fetch_add(&g_depart, 1, __ATOMIC_ACQ_REL, __HIP_MEMORY_SCOPE_AGENT);
                if (d == NBATCH - 1) {
                    __hip_atomic_store(&g_arrive, 0, __ATOMIC_RELAXED, __HIP_MEMORY_SCOPE_AGENT);
                    __hip_atomic_store(&g_depart, 0, __ATOMIC_RELAXED, __HIP_MEMORY_SCOPE_AGENT);
                }
            }
            synced = true;
        }
        if (ch == 3) {
            // emotion preds (accE final) -> out + concC cols 0..6; spk -> col 7.
            if (col < 7) {
#pragma unroll
                for (int i = 0; i < 4; ++i) {
                    const int row = wv * 16 + q * 4 + i;
                    const float v = accE[i] + emo_b[col];
                    out[(size_t)(R0 + row) * NE_ + col] = v;
                    concC[row * CST + col] = (short)f2b(v);
                }
            } else if (col == 7) {
#pragma unroll
                for (int i = 0; i < 4; ++i) {
                    const int row = wv * 16 + q * 4 + i;
                    concC[row * CST + 7] = (short)f2b((float)spk[R0 + row]);
                }
            }
            // cols 8..255 of concC hold stale-but-finite bf16; Bt is zero there.
        }
        // stage Bt chunk (after barrier; exact 16B copy incl. pads)
        for (int s = tid; s < 396; s += 256)
            *(uint4*)((char*)btM + s * 16) =
                *(const uint4*)((const char*)(wsbt + ch * NJ * CST) + s * 16);
        __syncthreads();

#pragma unroll
        for (int kt = 0; kt < 8; ++kt) {
            const bf16x8 a = *(const bf16x8*)(concC + (wv * 16 + col) * CST + kt * 32 + q * 8);
            if (ch < 3) {
                const bf16x8 be = *(const bf16x8*)(btE + col * CST + kt * 32 + q * 8);
                accE = __builtin_amdgcn_mfma_f32_16x16x32_bf16(a, be, accE, 0, 0, 0);
            }
            const bf16x8 bm = *(const bf16x8*)(btM + col * CST + kt * 32 + q * 8);
            acc2 = __builtin_amdgcn_mfma_f32_16x16x32_bf16(a, bm, acc2, 0, 0, 0);
        }
        __syncthreads();
    }

    // scatter pc (C layout: col=lane&15, row=q*4+i) into pcT/pcE
#pragma unroll
    for (int i = 0; i < 4; ++i) {
        const int row = wv * 16 + q * 4 + i;
        if (col < 4)       pcT[row * 8 + col] = acc2[i];
        else if (col < 8)  pcE[row * 8 + (col - 4)] = acc2[i];
        else if (col < 10) pcT[row * 8 + 4 + (col - 8)] = acc2[i];
        else if (col < 12) pcE[row * 8 + 4 + (col - 10)] = acc2[i];
    }
    __syncthreads();

    // pairs: O(1) each from pcT/pcE
    const float bc0 = wsbc[0], bc1 = wsbc[1], bc2v = wsbc[2], bc3 = wsbc[3];
    const float gb0 = gate_b[0], gb1 = gate_b[1];
    float* oc = out + (size_t)NROW * NE_ + (size_t)b * PAIRS * 2;
    for (int p = tid; p < PAIRS; p += 256) {
        int end = (int)((sqrtf(8.0f * (float)p + 1.0f) - 1.0f) * 0.5f);
        while ((end + 1) * (end + 2) / 2 <= p) end++;
        while (end * (end + 1) / 2 > p) end--;
        const int tt = p - end * (end + 1) / 2;
        const float4 u0 = *(const float4*)(pcT + tt * 8);
        const float4 u1 = *(const float4*)(pcT + tt * 8 + 4);
        const float4 v0 = *(const float4*)(pcE + end * 8);
        const float4 v1 = *(const float4*)(pcE + end * 8 + 4);
        const float g0 = u1.x + v1.x + gb0;
        const float g1 = u1.y + v1.y + gb1;
        oc[p * 2]     = (u0.x + v0.x + bc0) * g0 + (u0.z + v0.z + bc2v) * g1;
        oc[p * 2 + 1] = (u0.y + v0.y + bc1) * g0 + (u0.w + v0.w + bc3) * g1;
    }
}

// ---------------------------------------------------------------------------
extern "C" void kernel_launch(void* const* d_in, const int* in_sizes, int n_in,
                              void* d_out, int out_size, void* d_ws, size_t ws_size,
                              hipStream_t stream) {
    const float* pooled = (const float*)d_in[0];
    const int*   spk    = (const int*)d_in[1];
    const float* emo_w  = (const float*)d_in[2];
    const float* emo_b  = (const float*)d_in[3];
    const float* gate_w = (const float*)d_in[4];
    const float* gate_b = (const float*)d_in[5];
    const float* exp_w1 = (const float*)d_in[6];
    const float* exp_b1 = (const float*)d_in[7];
    const float* exp_w2 = (const float*)d_in[8];
    const float* exp_b2 = (const float*)d_in[9];

    float* out = (float*)d_out;
    unsigned short* wsbt = (unsigned short*)d_ws;          // 4*12*264*2 = 25,344 B
    float* wsbc = (float*)((char*)d_ws + 4 * NJ * CST * 2); // 16 B, 16-aligned

    hipLaunchKernelGGL(kFused, dim3(NPUB + NBATCH), dim3(256), 0, stream,
                       pooled, spk, emo_w, emo_b, gate_w, gate_b,
                       exp_w1, exp_b1, exp_w2, exp_b2, out, wsbt, wsbc);
}